// Round 4
// baseline (315.695 us; speedup 1.0000x reference)
//
#include <hip/hip_runtime.h>

#define NXCD 8

__device__ __forceinline__ int xcc_id() {
    int x;
    asm volatile("s_getreg_b32 %0, hwreg(20, 0, 32)" : "=s"(x));  // HW_REG_XCC_ID
    return x & 7;
}

// pos[b,n,j] = sum_i rel[b,n,i] * basis[b,i,j]
__global__ void pos_kernel(const float* __restrict__ rel,
                           const float* __restrict__ basis,
                           float* __restrict__ pos,
                           int BN, int N) {
    int idx = blockIdx.x * blockDim.x + threadIdx.x;
    if (idx >= BN) return;
    int b = idx / N;
    const float* bm = basis + b * 9;
    float x = rel[idx * 3 + 0], y = rel[idx * 3 + 1], z = rel[idx * 3 + 2];
    pos[idx * 3 + 0] = x * bm[0] + y * bm[3] + z * bm[6];
    pos[idx * 3 + 1] = x * bm[1] + y * bm[4] + z * bm[7];
    pos[idx * 3 + 2] = x * bm[2] + y * bm[5] + z * bm[8];
}

// per-batch 3x3 inverse (adjugate / det)
__global__ void inv_kernel(const float* __restrict__ basis,
                           float* __restrict__ recip, int B) {
    int b = blockIdx.x * blockDim.x + threadIdx.x;
    if (b >= B) return;
    const float* m = basis + b * 9;
    float a00 = m[0], a01 = m[1], a02 = m[2];
    float a10 = m[3], a11 = m[4], a12 = m[5];
    float a20 = m[6], a21 = m[7], a22 = m[8];
    float c00 = a11 * a22 - a12 * a21;
    float c01 = -(a10 * a22 - a12 * a20);
    float c02 = a10 * a21 - a11 * a20;
    float det = a00 * c00 + a01 * c01 + a02 * c02;
    float id = 1.0f / det;
    float* r = recip + b * 9;
    r[0] = c00 * id;
    r[1] = (a02 * a21 - a01 * a22) * id;
    r[2] = (a01 * a12 - a02 * a11) * id;
    r[3] = c01 * id;
    r[4] = (a00 * a22 - a02 * a20) * id;
    r[5] = (a02 * a10 - a00 * a12) * id;
    r[6] = c02 * id;
    r[7] = (a01 * a20 - a00 * a21) * id;
    r[8] = (a00 * a11 - a01 * a10) * id;
}

// XCD-replicated scatter: each block atomics into its own XCD's replica with
// workgroup-scope atomics (executed in the local, XCD-private L2 — no per-op
// fabric RMW). No cache line is atomically touched by more than one XCD.
__global__ void edge_kernel_xcd(const float* __restrict__ pos,
                                const float* __restrict__ shifts,
                                const int* __restrict__ src,
                                const int* __restrict__ dst,
                                const int* __restrict__ bch,
                                float* __restrict__ carts,
                                int E, int N, int BN) {
    int e = blockIdx.x * blockDim.x + threadIdx.x;
    if (e >= E) return;
    float* cart = carts + (size_t)xcc_id() * BN * 3;
    int b = bch[e], s = src[e], d = dst[e];
    int base = b * N;
    const float* pd = pos + (size_t)(base + d) * 3;
    const float* ps = pos + (size_t)(base + s) * 3;
    float dx = pd[0] - ps[0] + shifts[(size_t)e * 3 + 0];
    float dy = pd[1] - ps[1] + shifts[(size_t)e * 3 + 1];
    float dz = pd[2] - ps[2] + shifts[(size_t)e * 3 + 2];
    float r = sqrtf(dx * dx + dy * dy + dz * dz);
    float pref = 2.0f * (r - 3.0f) / (r + 1e-8f);  // STRENGTH = 1.0, CUTOFF = 3.0
    float* c = cart + (size_t)(base + s) * 3;
    __hip_atomic_fetch_add(&c[0], pref * dx, __ATOMIC_RELAXED, __HIP_MEMORY_SCOPE_WORKGROUP);
    __hip_atomic_fetch_add(&c[1], pref * dy, __ATOMIC_RELAXED, __HIP_MEMORY_SCOPE_WORKGROUP);
    __hip_atomic_fetch_add(&c[2], pref * dz, __ATOMIC_RELAXED, __HIP_MEMORY_SCOPE_WORKGROUP);
}

// fallback: device-scope atomics into a single accumulator
__global__ void edge_kernel_dev(const float* __restrict__ pos,
                                const float* __restrict__ shifts,
                                const int* __restrict__ src,
                                const int* __restrict__ dst,
                                const int* __restrict__ bch,
                                float* __restrict__ cart,
                                int E, int N) {
    int e = blockIdx.x * blockDim.x + threadIdx.x;
    if (e >= E) return;
    int b = bch[e], s = src[e], d = dst[e];
    int base = b * N;
    const float* pd = pos + (size_t)(base + d) * 3;
    const float* ps = pos + (size_t)(base + s) * 3;
    float dx = pd[0] - ps[0] + shifts[(size_t)e * 3 + 0];
    float dy = pd[1] - ps[1] + shifts[(size_t)e * 3 + 1];
    float dz = pd[2] - ps[2] + shifts[(size_t)e * 3 + 2];
    float r = sqrtf(dx * dx + dy * dy + dz * dz);
    float pref = 2.0f * (r - 3.0f) / (r + 1e-8f);
    float* c = cart + (size_t)(base + s) * 3;
    atomicAdd(&c[0], pref * dx);
    atomicAdd(&c[1], pref * dy);
    atomicAdd(&c[2], pref * dz);
}

// sum NR replicas, transform to relative coords, add raw scores
__global__ void reduce_out_kernel(const float* __restrict__ carts,
                                  const float* __restrict__ recip,
                                  const float* __restrict__ raw,
                                  float* __restrict__ out,
                                  int BN, int N, int NR) {
    int idx = blockIdx.x * blockDim.x + threadIdx.x;
    if (idx >= BN) return;
    float x = 0.0f, y = 0.0f, z = 0.0f;
    for (int rr = 0; rr < NR; ++rr) {
        const float* c = carts + ((size_t)rr * BN + idx) * 3;
        x += c[0]; y += c[1]; z += c[2];
    }
    int b = idx / N;
    const float* rm = recip + b * 9;
    out[idx * 3 + 0] = raw[idx * 3 + 0] + x * rm[0] + y * rm[3] + z * rm[6];
    out[idx * 3 + 1] = raw[idx * 3 + 1] + x * rm[1] + y * rm[4] + z * rm[7];
    out[idx * 3 + 2] = raw[idx * 3 + 2] + x * rm[2] + y * rm[5] + z * rm[8];
}

extern "C" void kernel_launch(void* const* d_in, const int* in_sizes, int n_in,
                              void* d_out, int out_size, void* d_ws, size_t ws_size,
                              hipStream_t stream) {
    const float* rel    = (const float*)d_in[0];
    const float* basis  = (const float*)d_in[1];
    const float* shifts = (const float*)d_in[2];
    const float* raw    = (const float*)d_in[3];
    const int*   src    = (const int*)d_in[4];
    const int*   dst    = (const int*)d_in[5];
    const int*   bch    = (const int*)d_in[6];

    int B  = in_sizes[1] / 9;
    int BN = in_sizes[0] / 3;
    int N  = BN / B;
    int E  = in_sizes[4];

    size_t posN = (size_t)BN * 3;  // floats
    size_t need = (posN + 144 + (size_t)NXCD * posN) * sizeof(float);

    float* pos   = (float*)d_ws;
    float* recip = pos + posN;
    float* carts = recip + 144;  // replica region

    pos_kernel<<<(BN + 255) / 256, 256, 0, stream>>>(rel, basis, pos, BN, N);
    inv_kernel<<<1, 64, 0, stream>>>(basis, recip, B);

    if (ws_size >= need) {
        // fast path: per-XCD replicas, local-L2 atomics
        hipMemsetAsync(carts, 0, (size_t)NXCD * posN * sizeof(float), stream);
        edge_kernel_xcd<<<(E + 255) / 256, 256, 0, stream>>>(pos, shifts, src, dst, bch,
                                                             carts, E, N, BN);
        reduce_out_kernel<<<(BN + 255) / 256, 256, 0, stream>>>(carts, recip, raw,
                                                                (float*)d_out, BN, N, NXCD);
    } else {
        // fallback: single accumulator, device-scope atomics
        hipMemsetAsync(carts, 0, posN * sizeof(float), stream);
        edge_kernel_dev<<<(E + 255) / 256, 256, 0, stream>>>(pos, shifts, src, dst, bch,
                                                             carts, E, N);
        reduce_out_kernel<<<(BN + 255) / 256, 256, 0, stream>>>(carts, recip, raw,
                                                                (float*)d_out, BN, N, 1);
    }
}

// Round 5
// 95.472 us; speedup vs baseline: 3.3067x; 3.3067x over previous
//
#include <hip/hip_runtime.h>

// ---- fast-path compile-time geometry (gated on BN==65536) ----
#define NPB     128        // nodes per coarse bucket
#define NCOARSE 512        // 65536 / 128
#define NB      1024       // scatter/hist blocks
#define SCAN_BS 1024       // elements per scan1 block

// pos[b,n,j] = sum_i rel[b,n,i] * basis[b,i,j]
__global__ void pos_kernel(const float* __restrict__ rel,
                           const float* __restrict__ basis,
                           float* __restrict__ pos,
                           int BN, int N) {
    int idx = blockIdx.x * blockDim.x + threadIdx.x;
    if (idx >= BN) return;
    int b = idx / N;
    const float* bm = basis + b * 9;
    float x = rel[idx * 3 + 0], y = rel[idx * 3 + 1], z = rel[idx * 3 + 2];
    pos[idx * 3 + 0] = x * bm[0] + y * bm[3] + z * bm[6];
    pos[idx * 3 + 1] = x * bm[1] + y * bm[4] + z * bm[7];
    pos[idx * 3 + 2] = x * bm[2] + y * bm[5] + z * bm[8];
}

// Phase A: per-block histogram over 512 coarse buckets -> ghist[bucket*NB + blk]
__global__ void hist_kernel(const int* __restrict__ src,
                            const int* __restrict__ bch,
                            int* __restrict__ ghist,
                            int E, int N, int chunk) {
    __shared__ int h[NCOARSE];
    int tid = threadIdx.x, blk = blockIdx.x;
    for (int t = tid; t < NCOARSE; t += 256) h[t] = 0;
    __syncthreads();
    int lo = blk * chunk, hi = min(E, lo + chunk);
    for (int e = lo + tid; e < hi; e += 256) {
        int node = bch[e] * N + src[e];
        atomicAdd(&h[node >> 7], 1);
    }
    __syncthreads();
    for (int t = tid; t < NCOARSE; t += 256) ghist[t * NB + blk] = h[t];
}

// Phase B1: scan 1024-element tiles (exclusive, in place), emit tile sums
__global__ void scan1_kernel(int* __restrict__ g, int* __restrict__ bsums) {
    __shared__ int tp[256];
    int tid = threadIdx.x;
    int base = blockIdx.x * SCAN_BS + tid * 4;
    int v0 = g[base], v1 = g[base + 1], v2 = g[base + 2], v3 = g[base + 3];
    int s = v0 + v1 + v2 + v3;
    tp[tid] = s;
    for (int off = 1; off < 256; off <<= 1) {
        __syncthreads();
        int t = (tid >= off) ? tp[tid - off] : 0;
        __syncthreads();
        tp[tid] += t;
    }
    __syncthreads();
    int incl = tp[tid];
    int excl = incl - s;
    g[base]     = excl;
    g[base + 1] = excl + v0;
    g[base + 2] = excl + v0 + v1;
    g[base + 3] = excl + v0 + v1 + v2;
    if (tid == 255) bsums[blockIdx.x] = incl;
}

// Phase B2: exclusive scan of tile sums (n <= 1024), one block
__global__ void scan2_kernel(int* __restrict__ bsums, int n) {
    __shared__ int tp[1024];
    int tid = threadIdx.x;
    int v = (tid < n) ? bsums[tid] : 0;
    tp[tid] = v;
    for (int off = 1; off < 1024; off <<= 1) {
        __syncthreads();
        int t = (tid >= off) ? tp[tid - off] : 0;
        __syncthreads();
        tp[tid] += t;
    }
    __syncthreads();
    if (tid < n) bsums[tid] = tp[tid] - v;
}

// Phase C: recompute contribution, write record into its bucket region (LDS cursors)
__global__ void scatter_kernel(const float* __restrict__ pos,
                               const float* __restrict__ shifts,
                               const int* __restrict__ src,
                               const int* __restrict__ dst,
                               const int* __restrict__ bch,
                               const int* __restrict__ ghist,
                               const int* __restrict__ bsums,
                               float4* __restrict__ sorted,
                               int E, int N, int chunk) {
    __shared__ int cur[NCOARSE];
    int tid = threadIdx.x, blk = blockIdx.x;
    for (int t = tid; t < NCOARSE; t += 256) {
        int idx = t * NB + blk;
        cur[t] = ghist[idx] + bsums[idx >> 10];
    }
    __syncthreads();
    int lo = blk * chunk, hi = min(E, lo + chunk);
    for (int e = lo + tid; e < hi; e += 256) {
        int b = bch[e], s = src[e], d = dst[e];
        int base = b * N;
        int node = base + s;
        const float* pd = pos + (size_t)(base + d) * 3;
        const float* ps = pos + (size_t)node * 3;
        float dx = pd[0] - ps[0] + shifts[(size_t)e * 3 + 0];
        float dy = pd[1] - ps[1] + shifts[(size_t)e * 3 + 1];
        float dz = pd[2] - ps[2] + shifts[(size_t)e * 3 + 2];
        float r = sqrtf(dx * dx + dy * dy + dz * dz);
        float pref = 2.0f * (r - 3.0f) / (r + 1e-8f);  // STRENGTH=1, CUTOFF=3
        int slot = atomicAdd(&cur[node >> 7], 1);
        float4 rec;
        rec.x = pref * dx; rec.y = pref * dy; rec.z = pref * dz;
        rec.w = __int_as_float(node);
        sorted[slot] = rec;
    }
}

// Phase D: per bucket (128 nodes), accumulate in LDS, fuse inv(basis) + residual, write out
__global__ void reduce_out_kernel(const float4* __restrict__ sorted,
                                  const int* __restrict__ ghist,
                                  const int* __restrict__ bsums,
                                  const float* __restrict__ basis,
                                  const float* __restrict__ raw,
                                  float* __restrict__ out,
                                  int E, int N) {
    __shared__ float acc[NPB * 3];
    int tid = threadIdx.x, bkt = blockIdx.x;
    for (int i = tid; i < NPB * 3; i += 256) acc[i] = 0.0f;
    __syncthreads();
    int i0 = ghist[bkt * NB] + bsums[bkt];
    int i1 = (bkt + 1 < NCOARSE) ? (ghist[(bkt + 1) * NB] + bsums[bkt + 1]) : E;
    for (int i = i0 + tid; i < i1; i += 256) {
        float4 r = sorted[i];
        int node = __float_as_int(r.w);
        int nl = node & (NPB - 1);
        atomicAdd(&acc[nl * 3 + 0], r.x);
        atomicAdd(&acc[nl * 3 + 1], r.y);
        atomicAdd(&acc[nl * 3 + 2], r.z);
    }
    __syncthreads();
    // all nodes in this bucket share one batch (NPB divides N)
    int node0 = bkt * NPB;
    int b = node0 / N;
    const float* m = basis + b * 9;
    float a00 = m[0], a01 = m[1], a02 = m[2];
    float a10 = m[3], a11 = m[4], a12 = m[5];
    float a20 = m[6], a21 = m[7], a22 = m[8];
    float c00 = a11 * a22 - a12 * a21;
    float c01 = -(a10 * a22 - a12 * a20);
    float c02 = a10 * a21 - a11 * a20;
    float det = a00 * c00 + a01 * c01 + a02 * c02;
    float id = 1.0f / det;
    float rm0 = c00 * id;
    float rm1 = (a02 * a21 - a01 * a22) * id;
    float rm2 = (a01 * a12 - a02 * a11) * id;
    float rm3 = c01 * id;
    float rm4 = (a00 * a22 - a02 * a20) * id;
    float rm5 = (a02 * a10 - a00 * a12) * id;
    float rm6 = c02 * id;
    float rm7 = (a01 * a20 - a00 * a21) * id;
    float rm8 = (a00 * a11 - a01 * a10) * id;
    // 384 consecutive output floats, coalesced
    for (int f = tid; f < NPB * 3; f += 256) {
        int nl = f / 3, c = f % 3;
        float x = acc[nl * 3 + 0], y = acc[nl * 3 + 1], z = acc[nl * 3 + 2];
        float rmc0 = (c == 0) ? rm0 : (c == 1) ? rm1 : rm2;
        float rmc1 = (c == 0) ? rm3 : (c == 1) ? rm4 : rm5;
        float rmc2 = (c == 0) ? rm6 : (c == 1) ? rm7 : rm8;
        size_t o = (size_t)node0 * 3 + f;
        out[o] = raw[o] + x * rmc0 + y * rmc1 + z * rmc2;
    }
}

// ---------------- fallback (device atomics, proven path) ----------------
__global__ void inv_kernel(const float* __restrict__ basis,
                           float* __restrict__ recip, int B) {
    int b = blockIdx.x * blockDim.x + threadIdx.x;
    if (b >= B) return;
    const float* m = basis + b * 9;
    float a00 = m[0], a01 = m[1], a02 = m[2];
    float a10 = m[3], a11 = m[4], a12 = m[5];
    float a20 = m[6], a21 = m[7], a22 = m[8];
    float c00 = a11 * a22 - a12 * a21;
    float c01 = -(a10 * a22 - a12 * a20);
    float c02 = a10 * a21 - a11 * a20;
    float det = a00 * c00 + a01 * c01 + a02 * c02;
    float id = 1.0f / det;
    float* r = recip + b * 9;
    r[0] = c00 * id;
    r[1] = (a02 * a21 - a01 * a22) * id;
    r[2] = (a01 * a12 - a02 * a11) * id;
    r[3] = c01 * id;
    r[4] = (a00 * a22 - a02 * a20) * id;
    r[5] = (a02 * a10 - a00 * a12) * id;
    r[6] = c02 * id;
    r[7] = (a01 * a20 - a00 * a21) * id;
    r[8] = (a00 * a11 - a01 * a10) * id;
}

__global__ void edge_kernel_dev(const float* __restrict__ pos,
                                const float* __restrict__ shifts,
                                const int* __restrict__ src,
                                const int* __restrict__ dst,
                                const int* __restrict__ bch,
                                float* __restrict__ cart,
                                int E, int N) {
    int e = blockIdx.x * blockDim.x + threadIdx.x;
    if (e >= E) return;
    int b = bch[e], s = src[e], d = dst[e];
    int base = b * N;
    const float* pd = pos + (size_t)(base + d) * 3;
    const float* ps = pos + (size_t)(base + s) * 3;
    float dx = pd[0] - ps[0] + shifts[(size_t)e * 3 + 0];
    float dy = pd[1] - ps[1] + shifts[(size_t)e * 3 + 1];
    float dz = pd[2] - ps[2] + shifts[(size_t)e * 3 + 2];
    float r = sqrtf(dx * dx + dy * dy + dz * dz);
    float pref = 2.0f * (r - 3.0f) / (r + 1e-8f);
    float* c = cart + (size_t)(base + s) * 3;
    atomicAdd(&c[0], pref * dx);
    atomicAdd(&c[1], pref * dy);
    atomicAdd(&c[2], pref * dz);
}

__global__ void out_kernel(const float* __restrict__ cart,
                           const float* __restrict__ recip,
                           const float* __restrict__ raw,
                           float* __restrict__ out,
                           int BN, int N) {
    int idx = blockIdx.x * blockDim.x + threadIdx.x;
    if (idx >= BN) return;
    int b = idx / N;
    const float* rm = recip + b * 9;
    float x = cart[idx * 3 + 0], y = cart[idx * 3 + 1], z = cart[idx * 3 + 2];
    out[idx * 3 + 0] = raw[idx * 3 + 0] + x * rm[0] + y * rm[3] + z * rm[6];
    out[idx * 3 + 1] = raw[idx * 3 + 1] + x * rm[1] + y * rm[4] + z * rm[7];
    out[idx * 3 + 2] = raw[idx * 3 + 2] + x * rm[2] + y * rm[5] + z * rm[8];
}

extern "C" void kernel_launch(void* const* d_in, const int* in_sizes, int n_in,
                              void* d_out, int out_size, void* d_ws, size_t ws_size,
                              hipStream_t stream) {
    const float* rel    = (const float*)d_in[0];
    const float* basis  = (const float*)d_in[1];
    const float* shifts = (const float*)d_in[2];
    const float* raw    = (const float*)d_in[3];
    const int*   src    = (const int*)d_in[4];
    const int*   dst    = (const int*)d_in[5];
    const int*   bch    = (const int*)d_in[6];

    int B  = in_sizes[1] / 9;
    int BN = in_sizes[0] / 3;
    int N  = BN / B;
    int E  = in_sizes[4];

    // fast path layout: sorted[E] float4 | pos[BN*3] | ghist[NCOARSE*NB] | bsums[NCOARSE]
    size_t need = (size_t)E * 16 + (size_t)BN * 3 * 4 + (size_t)(NCOARSE * NB + NCOARSE) * 4;
    bool fast = (BN == NCOARSE * NPB) && (N % NPB == 0) && (ws_size >= need);

    if (fast) {
        float4* sorted = (float4*)d_ws;
        float*  pos    = (float*)(sorted + E);
        int*    ghist  = (int*)(pos + (size_t)BN * 3);
        int*    bsums  = ghist + NCOARSE * NB;
        int chunk = (E + NB - 1) / NB;

        pos_kernel<<<(BN + 255) / 256, 256, 0, stream>>>(rel, basis, pos, BN, N);
        hist_kernel<<<NB, 256, 0, stream>>>(src, bch, ghist, E, N, chunk);
        scan1_kernel<<<NCOARSE * NB / SCAN_BS, 256, 0, stream>>>(ghist, bsums);
        scan2_kernel<<<1, 1024, 0, stream>>>(bsums, NCOARSE * NB / SCAN_BS);
        scatter_kernel<<<NB, 256, 0, stream>>>(pos, shifts, src, dst, bch,
                                               ghist, bsums, sorted, E, N, chunk);
        reduce_out_kernel<<<NCOARSE, 256, 0, stream>>>(sorted, ghist, bsums, basis,
                                                       raw, (float*)d_out, E, N);
    } else {
        // fallback: device-scope atomics (known-good, ~315 us)
        float* pos   = (float*)d_ws;
        float* cart  = pos + (size_t)BN * 3;
        float* recip = cart + (size_t)BN * 3;
        hipMemsetAsync(cart, 0, (size_t)BN * 3 * sizeof(float), stream);
        pos_kernel<<<(BN + 255) / 256, 256, 0, stream>>>(rel, basis, pos, BN, N);
        inv_kernel<<<1, 64, 0, stream>>>(basis, recip, B);
        edge_kernel_dev<<<(E + 255) / 256, 256, 0, stream>>>(pos, shifts, src, dst, bch,
                                                             cart, E, N);
        out_kernel<<<(BN + 255) / 256, 256, 0, stream>>>(cart, recip, raw,
                                                         (float*)d_out, BN, N);
    }
}